// Round 4
// baseline (119.641 us; speedup 1.0000x reference)
//
#include <hip/hip_runtime.h>
#include <math.h>

namespace {

constexpr int B = 8;
constexpr int N = 8192;
constexpr int D = 1024;
constexpr int E = 4;
constexpr int BN = B * N;

__device__ __forceinline__ unsigned int orderkey(float p) {
    return __float_as_uint(p) | 0x80000000u;  // positive floats
}

// f64 exp, |x| <= ~8: ln2 hi/lo range reduction + degree-12 Taylor.
__device__ __forceinline__ double fast_exp64(double x) {
    const double L2E    = 1.4426950408889634074;
    const double LN2_HI = 6.93147180369123816490e-01;
    const double LN2_LO = 1.90821492927058770002e-10;
    const double nd = rint(x * L2E);
    double r = fma(-nd, LN2_HI, x);
    r = fma(-nd, LN2_LO, r);
    double p = 1.0 / 479001600.0;
    p = fma(p, r, 1.0 / 39916800.0);
    p = fma(p, r, 1.0 / 3628800.0);
    p = fma(p, r, 1.0 / 362880.0);
    p = fma(p, r, 1.0 / 40320.0);
    p = fma(p, r, 1.0 / 5040.0);
    p = fma(p, r, 1.0 / 720.0);
    p = fma(p, r, 1.0 / 120.0);
    p = fma(p, r, 1.0 / 24.0);
    p = fma(p, r, 1.0 / 6.0);
    p = fma(p, r, 0.5);
    p = fma(p, r, 1.0);
    p = fma(p, r, 1.0);
    const long long sc = ((long long)(1023 + (int)nd)) << 52;
    return p * __longlong_as_double(sc);
}

// ---------------------------------------------------------------------------
// Kernel 1: logits via f64 FMA vs LDS-resident f64 W, 4-token blocking so each
// W quad is read ONCE per 4 tokens (ds_read per token drops 32 -> 8).
// FMA order per (token, expert) is bitwise-identical to the verified R3
// kernel (c ascending; x,y,z,w within quad), as are butterfly and softmax.
// ---------------------------------------------------------------------------
__global__ __launch_bounds__(256, 2) void probs_kernel(
    const float* __restrict__ x,     // [BN, D]
    const float* __restrict__ W,     // [E, D]
    const float* __restrict__ bias,  // [E]
    float* __restrict__ probs_t)     // [B, E, N]
{
    __shared__ double2 s_WA[E][D / 4];  // 16 KB  (w.x, w.y of each quad)
    __shared__ double2 s_WB[E][D / 4];  // 16 KB  (w.z, w.w)
    __shared__ double s_l[64][4];       // 2 KB   per-token logits

    {
        const float4* W4 = reinterpret_cast<const float4*>(W);
        for (int i = threadIdx.x; i < E * D / 4; i += 256) {
            const int e = i >> 8, q = i & 255;
            const float4 w = W4[i];
            s_WA[e][q] = make_double2((double)w.x, (double)w.y);
            s_WB[e][q] = make_double2((double)w.z, (double)w.w);
        }
    }
    __syncthreads();

    const int lane = threadIdx.x & 63;
    const int wv = threadIdx.x >> 6;
    const int tok0 = blockIdx.x * 64 + wv * 16;           // 16 tokens per wave
    const int j = ((lane & 1) << 1) | ((lane >> 1) & 1);  // expert after split

    const float4* x4 = reinterpret_cast<const float4*>(x);

    float4 cur[4][4], nxt[4][4];  // [token-in-group][quad-chunk]
#pragma unroll
    for (int t = 0; t < 4; ++t) {
        const float4* xv = x4 + (size_t)(tok0 + t) * (D / 4);
#pragma unroll
        for (int c = 0; c < 4; ++c) cur[t][c] = xv[lane + 64 * c];
    }

    for (int g = 0; g < 4; ++g) {  // 4 groups of 4 tokens
        if (g < 3) {               // prefetch next group
#pragma unroll
            for (int t = 0; t < 4; ++t) {
                const float4* xv = x4 + (size_t)(tok0 + (g + 1) * 4 + t) * (D / 4);
#pragma unroll
                for (int c = 0; c < 4; ++c) nxt[t][c] = xv[lane + 64 * c];
            }
        }

        double acc[4][4];  // [token][expert]
#pragma unroll
        for (int t = 0; t < 4; ++t)
#pragma unroll
            for (int e = 0; e < 4; ++e) acc[t][e] = 0.0;

#pragma unroll
        for (int c = 0; c < 4; ++c) {
            const int idx = lane + 64 * c;
            double xd[4][4];
#pragma unroll
            for (int t = 0; t < 4; ++t) {
                xd[t][0] = (double)cur[t][c].x;
                xd[t][1] = (double)cur[t][c].y;
                xd[t][2] = (double)cur[t][c].z;
                xd[t][3] = (double)cur[t][c].w;
            }
#pragma unroll
            for (int e = 0; e < 4; ++e) {
                const double2 wA = s_WA[e][idx];
                const double2 wB = s_WB[e][idx];
#pragma unroll
                for (int t = 0; t < 4; ++t) {
                    acc[t][e] = fma(xd[t][0], wA.x, acc[t][e]);
                    acc[t][e] = fma(xd[t][1], wA.y, acc[t][e]);
                    acc[t][e] = fma(xd[t][2], wB.x, acc[t][e]);
                    acc[t][e] = fma(xd[t][3], wB.y, acc[t][e]);
                }
            }
        }

        // Value-split butterfly per token (identical to verified version).
#pragma unroll
        for (int t = 0; t < 4; ++t) {
            const double a0 = acc[t][0], a1 = acc[t][1];
            const double a2 = acc[t][2], a3 = acc[t][3];
            const double v = (lane & 1) ? a0 : a2;
            const double w = (lane & 1) ? a1 : a3;
            const double sv = __shfl_xor(v, 1, 64);
            const double sw = __shfl_xor(w, 1, 64);
            const double s0 = (lane & 1) ? (a2 + sv) : (a0 + sv);
            const double s1 = (lane & 1) ? (a3 + sw) : (a1 + sw);
            const double tt = (lane & 2) ? s0 : s1;
            const double st = __shfl_xor(tt, 2, 64);
            double s = (lane & 2) ? (s1 + st) : (s0 + st);
            s += __shfl_xor(s, 4, 64);
            s += __shfl_xor(s, 8, 64);
            s += __shfl_xor(s, 16, 64);
            s += __shfl_xor(s, 32, 64);
            if (lane < 4) s_l[wv * 16 + g * 4 + t][j] = s;
        }

#pragma unroll
        for (int t = 0; t < 4; ++t)
#pragma unroll
            for (int c = 0; c < 4; ++c) cur[t][c] = nxt[t][c];
    }
    __syncthreads();

    // Phase 2: thread -> (token tid>>2, expert tid&3); exp/div fully parallel.
    {
        const int tok = threadIdx.x >> 2;
        const int e = threadIdx.x & 3;
        const double l0 = s_l[tok][0] + (double)bias[0];
        const double l1 = s_l[tok][1] + (double)bias[1];
        const double l2 = s_l[tok][2] + (double)bias[2];
        const double l3 = s_l[tok][3] + (double)bias[3];
        const double m = fmax(fmax(l0, l1), fmax(l2, l3));
        const double le = (e == 0) ? l0 : (e == 1) ? l1 : (e == 2) ? l2 : l3;
        const double ex = fast_exp64(le - m);
        double Z = ex + __shfl_xor(ex, 1, 64);
        Z += __shfl_xor(Z, 2, 64);
        const double p = ex / Z;
        const int token = blockIdx.x * 64 + tok;
        const int brow = token >> 13;
        const int n = token & (N - 1);
        probs_t[((size_t)brow * E + e) * N + n] = (float)p;
    }
}

// ---------------------------------------------------------------------------
// Kernel 2: capacity-constrained expert-preferred routing (verified, as R2).
// ---------------------------------------------------------------------------
__global__ __launch_bounds__(1024) void route_kernel(
    const float* __restrict__ probs_t,  // [B, E, N]
    float* __restrict__ out)            // [2*B*N]: mask (as float), then probs
{
    constexpr int TPB = 1024;
    constexpr int ITEMS = N / TPB;  // 8
    constexpr int NBKT = 4096;
    constexpr int CMAX = 64;

    __shared__ unsigned short s_bkt[N];      // 16 KB
    __shared__ unsigned char s_exp[N];       // 8 KB, 255 = unassigned
    __shared__ unsigned int s_hist[NBKT];    // 16 KB
    __shared__ unsigned int s_cand[CMAX];
    __shared__ unsigned int s_ckey[CMAX];
    __shared__ unsigned int s_wsum[32];
    __shared__ unsigned int s_sel[3];

    const int b = blockIdx.x;
    const int t = threadIdx.x;
    const int lane = t & 63;
    const int wv = t >> 6;

    for (int u = 0; u < ITEMS; ++u) s_exp[t * ITEMS + u] = 255;

    const int kcap[E] = {819, 1228, 2048, 4096};
    int nun = N;

    for (int j = E - 1; j >= 0; --j) {
        const int kk = min(kcap[j], nun);
        const float* pj = probs_t + ((size_t)b * E + j) * N;

        for (int u = 0; u < NBKT / TPB; ++u) s_hist[t + u * TPB] = 0;
        if (t == 0) s_sel[2] = 0;
        __syncthreads();

        for (int u = 0; u < ITEMS; ++u) {
            const int i = t * ITEMS + u;
            const float p = pj[i];
            int bk = (int)(p * 4096.0f);
            bk = bk > 4095 ? 4095 : (bk < 0 ? 0 : bk);
            s_bkt[i] = (unsigned short)bk;
            if (s_exp[i] == 255) atomicAdd(&s_hist[bk], 1u);
        }
        __syncthreads();

        const unsigned int h0 = s_hist[4 * t], h1 = s_hist[4 * t + 1];
        const unsigned int h2 = s_hist[4 * t + 2], h3 = s_hist[4 * t + 3];
        const unsigned int lsum = h0 + h1 + h2 + h3;
        unsigned int sfx = lsum;
#pragma unroll
        for (int off = 1; off < 64; off <<= 1) {
            const unsigned int vv = __shfl_down(sfx, off, 64);
            if (lane + off < 64) sfx += vv;
        }
        if (lane == 0) s_wsum[wv] = sfx;
        __syncthreads();
        if (t < 16) {
            unsigned int acc = 0;
            for (int w2 = t + 1; w2 < 16; ++w2) acc += s_wsum[w2];
            s_wsum[16 + t] = acc;
        }
        __syncthreads();
        {
            unsigned int run = (sfx - lsum) + s_wsum[16 + wv];
            const unsigned int hh[4] = {h0, h1, h2, h3};
#pragma unroll
            for (int bi = 3; bi >= 0; --bi) {
                const unsigned int h = hh[bi];
                if (run < (unsigned)kk && run + h >= (unsigned)kk) {
                    s_sel[0] = (unsigned)(4 * t + bi);
                    s_sel[1] = (unsigned)kk - run;
                }
                run += h;
            }
        }
        __syncthreads();
        const int Bstar = (int)s_sel[0];
        const unsigned int rem = s_sel[1];

        for (int u = 0; u < ITEMS; ++u) {
            const int i = t * ITEMS + u;
            if (s_exp[i] != 255) continue;
            const int bk = s_bkt[i];
            if (bk > Bstar) {
                s_exp[i] = (unsigned char)j;
            } else if (bk == Bstar) {
                const unsigned int pos = atomicAdd(&s_sel[2], 1u);
                if (pos < CMAX) { s_cand[pos] = (unsigned int)i; s_ckey[pos] = orderkey(pj[i]); }
            }
        }
        __syncthreads();
        const unsigned int c = s_sel[2];

        if (rem == c) {
            for (int u = 0; u < ITEMS; ++u) {
                const int i = t * ITEMS + u;
                if (s_exp[i] == 255 && s_bkt[i] == Bstar) s_exp[i] = (unsigned char)j;
            }
            __syncthreads();
        } else if (c <= CMAX) {
            if (wv == 0) {
                unsigned int key = 0u, idx = 0xFFFFFFFFu;
                if (lane < (int)c) { key = s_ckey[lane]; idx = s_cand[lane]; }
                unsigned long long v = ((unsigned long long)(~key) << 32) | idx;
                for (int k2 = 2; k2 <= 64; k2 <<= 1) {
                    for (int jj = k2 >> 1; jj >= 1; jj >>= 1) {
                        const unsigned long long pv = __shfl_xor(v, jj, 64);
                        const bool up = ((lane & k2) == 0);
                        const bool lower = ((lane & jj) == 0);
                        if (lower == up) v = (v < pv) ? v : pv;
                        else             v = (v > pv) ? v : pv;
                    }
                }
                if (lane < (int)rem) {
                    const unsigned int tok = (unsigned int)(v & 0xFFFFFFFFu);
                    s_exp[tok] = (unsigned char)j;
                }
            }
            __syncthreads();
        } else {
            unsigned int prefix = 0, remR = rem;
            for (int shift = 24; shift >= 0; shift -= 8) {
                if (t < 256) s_hist[t] = 0;
                __syncthreads();
                for (int u = 0; u < ITEMS; ++u) {
                    const int i = t * ITEMS + u;
                    if (s_exp[i] != 255) continue;
                    const unsigned int key = orderkey(pj[i]);
                    if (shift == 24 || (key >> (shift + 8)) == prefix)
                        atomicAdd(&s_hist[(key >> shift) & 255u], 1u);
                }
                __syncthreads();
                if (wv == 0) {
                    const unsigned int g0 = s_hist[4 * lane], g1 = s_hist[4 * lane + 1];
                    const unsigned int g2 = s_hist[4 * lane + 2], g3 = s_hist[4 * lane + 3];
                    const unsigned int ls = g0 + g1 + g2 + g3;
                    unsigned int sx = ls;
#pragma unroll
                    for (int off = 1; off < 64; off <<= 1) {
                        const unsigned int vv = __shfl_down(sx, off, 64);
                        if (lane + off < 64) sx += vv;
                    }
                    unsigned int rr = sx - ls;
                    const unsigned int gg[4] = {g0, g1, g2, g3};
#pragma unroll
                    for (int bi = 3; bi >= 0; --bi) {
                        const unsigned int h = gg[bi];
                        if (rr < remR && rr + h >= remR) {
                            s_sel[0] = (unsigned)(4 * lane + bi);
                            s_sel[1] = remR - rr;
                        }
                        rr += h;
                    }
                }
                __syncthreads();
                prefix = (prefix << 8) | s_sel[0];
                remR = s_sel[1];
            }
            const unsigned int T = prefix;
            unsigned int local = 0;
            for (int u = 0; u < ITEMS; ++u) {
                const int i = t * ITEMS + u;
                if (s_exp[i] == 255 && orderkey(pj[i]) == T) ++local;
            }
            unsigned int inc = local;
#pragma unroll
            for (int off = 1; off < 64; off <<= 1) {
                const unsigned int vv = __shfl_up(inc, off, 64);
                if (lane >= off) inc += vv;
            }
            if (lane == 63) s_wsum[wv] = inc;
            __syncthreads();
            if (t < 16) {
                unsigned int a2 = 0;
                for (int w2 = 0; w2 < t; ++w2) a2 += s_wsum[w2];
                s_wsum[16 + t] = a2;
            }
            __syncthreads();
            unsigned int taken = (inc - local) + s_wsum[16 + wv];
            for (int u = 0; u < ITEMS; ++u) {
                const int i = t * ITEMS + u;
                if (s_exp[i] != 255) continue;
                const unsigned int key = orderkey(pj[i]);
                if (key > T) {
                    s_exp[i] = (unsigned char)j;
                } else if (key == T) {
                    if (taken < remR) s_exp[i] = (unsigned char)j;
                    ++taken;
                }
            }
            __syncthreads();
        }
        nun -= kk;
    }

    float* out_mask = out;
    float* out_p = out + (size_t)BN;
    for (int u = 0; u < ITEMS; ++u) {
        const int i = t * ITEMS + u;
        int e = s_exp[i];
        if (e == 255) e = 0;
        out_mask[(size_t)b * N + i] = (float)e;
        out_p[(size_t)b * N + i] = probs_t[((size_t)b * E + e) * N + i];
    }
}

}  // namespace

extern "C" void kernel_launch(void* const* d_in, const int* in_sizes, int n_in,
                              void* d_out, int out_size, void* d_ws, size_t ws_size,
                              hipStream_t stream) {
    const float* x = (const float*)d_in[0];     // [B, N, D]
    const float* W = (const float*)d_in[1];     // [E, D]
    const float* bias = (const float*)d_in[2];  // [E]
    float* out = (float*)d_out;                 // [2*B*N] floats
    float* probs_t = (float*)d_ws;              // [B, E, N] fp32, 1 MB

    probs_kernel<<<BN / 64, 256, 0, stream>>>(x, W, bias, probs_t);
    route_kernel<<<B, 1024, 0, stream>>>(probs_t, out);
}

// Round 5
// 83.624 us; speedup vs baseline: 1.4307x; 1.4307x over previous
//
#include <hip/hip_runtime.h>
#include <math.h>

namespace {

constexpr int B = 8;
constexpr int N = 8192;
constexpr int D = 1024;
constexpr int E = 4;
constexpr int BN = B * N;

__device__ __forceinline__ unsigned int orderkey(float p) {
    return __float_as_uint(p) | 0x80000000u;  // positive floats
}

// f64 exp, |x| <= ~8: ln2 hi/lo range reduction + degree-12 Taylor.
__device__ __forceinline__ double fast_exp64(double x) {
    const double L2E    = 1.4426950408889634074;
    const double LN2_HI = 6.93147180369123816490e-01;
    const double LN2_LO = 1.90821492927058770002e-10;
    const double nd = rint(x * L2E);
    double r = fma(-nd, LN2_HI, x);
    r = fma(-nd, LN2_LO, r);
    double p = 1.0 / 479001600.0;
    p = fma(p, r, 1.0 / 39916800.0);
    p = fma(p, r, 1.0 / 3628800.0);
    p = fma(p, r, 1.0 / 362880.0);
    p = fma(p, r, 1.0 / 40320.0);
    p = fma(p, r, 1.0 / 5040.0);
    p = fma(p, r, 1.0 / 720.0);
    p = fma(p, r, 1.0 / 120.0);
    p = fma(p, r, 1.0 / 24.0);
    p = fma(p, r, 1.0 / 6.0);
    p = fma(p, r, 0.5);
    p = fma(p, r, 1.0);
    p = fma(p, r, 1.0);
    const long long sc = ((long long)(1023 + (int)nd)) << 52;
    return p * __longlong_as_double(sc);
}

// ---------------------------------------------------------------------------
// Kernel 1: logits via f64 FMA with W held in per-lane f64 REGISTERS (128
// VGPR) -- no LDS traffic in the token loop except the 7-shuffle butterfly.
// Token loop, butterfly, and softmax are numerically identical to the
// verified R3 kernel (same FMA order: c ascending; x,y,z,w within quad).
// VGPR budget: 128 (W) + 32 (x cur/nxt) + 8 (acc) + 8 (cvt) + ~20 ≈ 196.
// ---------------------------------------------------------------------------
__global__ __launch_bounds__(256, 2) void probs_kernel(
    const float* __restrict__ x,     // [BN, D]
    const float* __restrict__ W,     // [E, D]
    const float* __restrict__ bias,  // [E]
    float* __restrict__ probs_t)     // [B, E, N]
{
    __shared__ double s_l[64][4];  // 2 KB  per-token logits

    const int lane = threadIdx.x & 63;
    const int wv = threadIdx.x >> 6;
    const int tok0 = blockIdx.x * 64 + wv * 16;           // 16 tokens per wave
    const int j = ((lane & 1) << 1) | ((lane >> 1) & 1);  // expert after split

    // Per-lane W fragment -> f64 registers. W is 16 KB, L2/L3 resident.
    double wreg[4][4][4];  // [expert][chunk][elem]  (all indices unroll-const)
    {
        const float4* W4 = reinterpret_cast<const float4*>(W);
#pragma unroll
        for (int e = 0; e < 4; ++e)
#pragma unroll
            for (int c = 0; c < 4; ++c) {
                const float4 w = W4[e * 256 + lane + 64 * c];
                wreg[e][c][0] = (double)w.x;
                wreg[e][c][1] = (double)w.y;
                wreg[e][c][2] = (double)w.z;
                wreg[e][c][3] = (double)w.w;
            }
    }

    const float4* x4 = reinterpret_cast<const float4*>(x);

    float4 c0, c1, c2, c3;
    {
        const float4* xv = x4 + (size_t)tok0 * (D / 4);
        c0 = xv[lane]; c1 = xv[lane + 64]; c2 = xv[lane + 128]; c3 = xv[lane + 192];
    }

    for (int k = 0; k < 16; ++k) {
        float4 n0, n1, n2, n3;
        if (k < 15) {  // prefetch next token
            const float4* xv = x4 + (size_t)(tok0 + k + 1) * (D / 4);
            n0 = xv[lane]; n1 = xv[lane + 64]; n2 = xv[lane + 128]; n3 = xv[lane + 192];
        }

        double a0 = 0.0, a1 = 0.0, a2 = 0.0, a3 = 0.0;
#define CHUNK(XC, CI)                                                        \
        {                                                                    \
            const double xx = (double)(XC).x, xy = (double)(XC).y;           \
            const double xz = (double)(XC).z, xw = (double)(XC).w;           \
            a0 = fma(xx, wreg[0][CI][0], a0); a0 = fma(xy, wreg[0][CI][1], a0); \
            a0 = fma(xz, wreg[0][CI][2], a0); a0 = fma(xw, wreg[0][CI][3], a0); \
            a1 = fma(xx, wreg[1][CI][0], a1); a1 = fma(xy, wreg[1][CI][1], a1); \
            a1 = fma(xz, wreg[1][CI][2], a1); a1 = fma(xw, wreg[1][CI][3], a1); \
            a2 = fma(xx, wreg[2][CI][0], a2); a2 = fma(xy, wreg[2][CI][1], a2); \
            a2 = fma(xz, wreg[2][CI][2], a2); a2 = fma(xw, wreg[2][CI][3], a2); \
            a3 = fma(xx, wreg[3][CI][0], a3); a3 = fma(xy, wreg[3][CI][1], a3); \
            a3 = fma(xz, wreg[3][CI][2], a3); a3 = fma(xw, wreg[3][CI][3], a3); \
        }
        CHUNK(c0, 0) CHUNK(c1, 1) CHUNK(c2, 2) CHUNK(c3, 3)
#undef CHUNK

        // Value-split butterfly (identical to verified version).
        {
            const double v = (lane & 1) ? a0 : a2;
            const double w = (lane & 1) ? a1 : a3;
            const double sv = __shfl_xor(v, 1, 64);
            const double sw = __shfl_xor(w, 1, 64);
            const double s0 = (lane & 1) ? (a2 + sv) : (a0 + sv);
            const double s1 = (lane & 1) ? (a3 + sw) : (a1 + sw);
            const double tt = (lane & 2) ? s0 : s1;
            const double st = __shfl_xor(tt, 2, 64);
            double s = (lane & 2) ? (s1 + st) : (s0 + st);
            s += __shfl_xor(s, 4, 64);
            s += __shfl_xor(s, 8, 64);
            s += __shfl_xor(s, 16, 64);
            s += __shfl_xor(s, 32, 64);
            if (lane < 4) s_l[wv * 16 + k][j] = s;
        }

        c0 = n0; c1 = n1; c2 = n2; c3 = n3;
    }
    __syncthreads();

    // Phase 2: thread -> (token tid>>2, expert tid&3); exp/div fully parallel.
    {
        const int tok = threadIdx.x >> 2;
        const int e = threadIdx.x & 3;
        const double l0 = s_l[tok][0] + (double)bias[0];
        const double l1 = s_l[tok][1] + (double)bias[1];
        const double l2 = s_l[tok][2] + (double)bias[2];
        const double l3 = s_l[tok][3] + (double)bias[3];
        const double m = fmax(fmax(l0, l1), fmax(l2, l3));
        const double le = (e == 0) ? l0 : (e == 1) ? l1 : (e == 2) ? l2 : l3;
        const double ex = fast_exp64(le - m);
        double Z = ex + __shfl_xor(ex, 1, 64);
        Z += __shfl_xor(Z, 2, 64);
        const double p = ex / Z;
        const int token = blockIdx.x * 64 + tok;
        const int brow = token >> 13;
        const int n = token & (N - 1);
        probs_t[((size_t)brow * E + e) * N + n] = (float)p;
    }
}

// ---------------------------------------------------------------------------
// Kernel 2: capacity-constrained expert-preferred routing (verified, as R2).
// ---------------------------------------------------------------------------
__global__ __launch_bounds__(1024) void route_kernel(
    const float* __restrict__ probs_t,  // [B, E, N]
    float* __restrict__ out)            // [2*B*N]: mask (as float), then probs
{
    constexpr int TPB = 1024;
    constexpr int ITEMS = N / TPB;  // 8
    constexpr int NBKT = 4096;
    constexpr int CMAX = 64;

    __shared__ unsigned short s_bkt[N];      // 16 KB
    __shared__ unsigned char s_exp[N];       // 8 KB, 255 = unassigned
    __shared__ unsigned int s_hist[NBKT];    // 16 KB
    __shared__ unsigned int s_cand[CMAX];
    __shared__ unsigned int s_ckey[CMAX];
    __shared__ unsigned int s_wsum[32];
    __shared__ unsigned int s_sel[3];

    const int b = blockIdx.x;
    const int t = threadIdx.x;
    const int lane = t & 63;
    const int wv = t >> 6;

    for (int u = 0; u < ITEMS; ++u) s_exp[t * ITEMS + u] = 255;

    const int kcap[E] = {819, 1228, 2048, 4096};
    int nun = N;

    for (int j = E - 1; j >= 0; --j) {
        const int kk = min(kcap[j], nun);
        const float* pj = probs_t + ((size_t)b * E + j) * N;

        for (int u = 0; u < NBKT / TPB; ++u) s_hist[t + u * TPB] = 0;
        if (t == 0) s_sel[2] = 0;
        __syncthreads();

        for (int u = 0; u < ITEMS; ++u) {
            const int i = t * ITEMS + u;
            const float p = pj[i];
            int bk = (int)(p * 4096.0f);
            bk = bk > 4095 ? 4095 : (bk < 0 ? 0 : bk);
            s_bkt[i] = (unsigned short)bk;
            if (s_exp[i] == 255) atomicAdd(&s_hist[bk], 1u);
        }
        __syncthreads();

        const unsigned int h0 = s_hist[4 * t], h1 = s_hist[4 * t + 1];
        const unsigned int h2 = s_hist[4 * t + 2], h3 = s_hist[4 * t + 3];
        const unsigned int lsum = h0 + h1 + h2 + h3;
        unsigned int sfx = lsum;
#pragma unroll
        for (int off = 1; off < 64; off <<= 1) {
            const unsigned int vv = __shfl_down(sfx, off, 64);
            if (lane + off < 64) sfx += vv;
        }
        if (lane == 0) s_wsum[wv] = sfx;
        __syncthreads();
        if (t < 16) {
            unsigned int acc = 0;
            for (int w2 = t + 1; w2 < 16; ++w2) acc += s_wsum[w2];
            s_wsum[16 + t] = acc;
        }
        __syncthreads();
        {
            unsigned int run = (sfx - lsum) + s_wsum[16 + wv];
            const unsigned int hh[4] = {h0, h1, h2, h3};
#pragma unroll
            for (int bi = 3; bi >= 0; --bi) {
                const unsigned int h = hh[bi];
                if (run < (unsigned)kk && run + h >= (unsigned)kk) {
                    s_sel[0] = (unsigned)(4 * t + bi);
                    s_sel[1] = (unsigned)kk - run;
                }
                run += h;
            }
        }
        __syncthreads();
        const int Bstar = (int)s_sel[0];
        const unsigned int rem = s_sel[1];

        for (int u = 0; u < ITEMS; ++u) {
            const int i = t * ITEMS + u;
            if (s_exp[i] != 255) continue;
            const int bk = s_bkt[i];
            if (bk > Bstar) {
                s_exp[i] = (unsigned char)j;
            } else if (bk == Bstar) {
                const unsigned int pos = atomicAdd(&s_sel[2], 1u);
                if (pos < CMAX) { s_cand[pos] = (unsigned int)i; s_ckey[pos] = orderkey(pj[i]); }
            }
        }
        __syncthreads();
        const unsigned int c = s_sel[2];

        if (rem == c) {
            for (int u = 0; u < ITEMS; ++u) {
                const int i = t * ITEMS + u;
                if (s_exp[i] == 255 && s_bkt[i] == Bstar) s_exp[i] = (unsigned char)j;
            }
            __syncthreads();
        } else if (c <= CMAX) {
            if (wv == 0) {
                unsigned int key = 0u, idx = 0xFFFFFFFFu;
                if (lane < (int)c) { key = s_ckey[lane]; idx = s_cand[lane]; }
                unsigned long long v = ((unsigned long long)(~key) << 32) | idx;
                for (int k2 = 2; k2 <= 64; k2 <<= 1) {
                    for (int jj = k2 >> 1; jj >= 1; jj >>= 1) {
                        const unsigned long long pv = __shfl_xor(v, jj, 64);
                        const bool up = ((lane & k2) == 0);
                        const bool lower = ((lane & jj) == 0);
                        if (lower == up) v = (v < pv) ? v : pv;
                        else             v = (v > pv) ? v : pv;
                    }
                }
                if (lane < (int)rem) {
                    const unsigned int tok = (unsigned int)(v & 0xFFFFFFFFu);
                    s_exp[tok] = (unsigned char)j;
                }
            }
            __syncthreads();
        } else {
            unsigned int prefix = 0, remR = rem;
            for (int shift = 24; shift >= 0; shift -= 8) {
                if (t < 256) s_hist[t] = 0;
                __syncthreads();
                for (int u = 0; u < ITEMS; ++u) {
                    const int i = t * ITEMS + u;
                    if (s_exp[i] != 255) continue;
                    const unsigned int key = orderkey(pj[i]);
                    if (shift == 24 || (key >> (shift + 8)) == prefix)
                        atomicAdd(&s_hist[(key >> shift) & 255u], 1u);
                }
                __syncthreads();
                if (wv == 0) {
                    const unsigned int g0 = s_hist[4 * lane], g1 = s_hist[4 * lane + 1];
                    const unsigned int g2 = s_hist[4 * lane + 2], g3 = s_hist[4 * lane + 3];
                    const unsigned int ls = g0 + g1 + g2 + g3;
                    unsigned int sx = ls;
#pragma unroll
                    for (int off = 1; off < 64; off <<= 1) {
                        const unsigned int vv = __shfl_down(sx, off, 64);
                        if (lane + off < 64) sx += vv;
                    }
                    unsigned int rr = sx - ls;
                    const unsigned int gg[4] = {g0, g1, g2, g3};
#pragma unroll
                    for (int bi = 3; bi >= 0; --bi) {
                        const unsigned int h = gg[bi];
                        if (rr < remR && rr + h >= remR) {
                            s_sel[0] = (unsigned)(4 * lane + bi);
                            s_sel[1] = remR - rr;
                        }
                        rr += h;
                    }
                }
                __syncthreads();
                prefix = (prefix << 8) | s_sel[0];
                remR = s_sel[1];
            }
            const unsigned int T = prefix;
            unsigned int local = 0;
            for (int u = 0; u < ITEMS; ++u) {
                const int i = t * ITEMS + u;
                if (s_exp[i] == 255 && orderkey(pj[i]) == T) ++local;
            }
            unsigned int inc = local;
#pragma unroll
            for (int off = 1; off < 64; off <<= 1) {
                const unsigned int vv = __shfl_up(inc, off, 64);
                if (lane >= off) inc += vv;
            }
            if (lane == 63) s_wsum[wv] = inc;
            __syncthreads();
            if (t < 16) {
                unsigned int a2 = 0;
                for (int w2 = 0; w2 < t; ++w2) a2 += s_wsum[w2];
                s_wsum[16 + t] = a2;
            }
            __syncthreads();
            unsigned int taken = (inc - local) + s_wsum[16 + wv];
            for (int u = 0; u < ITEMS; ++u) {
                const int i = t * ITEMS + u;
                if (s_exp[i] != 255) continue;
                const unsigned int key = orderkey(pj[i]);
                if (key > T) {
                    s_exp[i] = (unsigned char)j;
                } else if (key == T) {
                    if (taken < remR) s_exp[i] = (unsigned char)j;
                    ++taken;
                }
            }
            __syncthreads();
        }
        nun -= kk;
    }

    float* out_mask = out;
    float* out_p = out + (size_t)BN;
    for (int u = 0; u < ITEMS; ++u) {
        const int i = t * ITEMS + u;
        int e = s_exp[i];
        if (e == 255) e = 0;
        out_mask[(size_t)b * N + i] = (float)e;
        out_p[(size_t)b * N + i] = probs_t[((size_t)b * E + e) * N + i];
    }
}

}  // namespace

extern "C" void kernel_launch(void* const* d_in, const int* in_sizes, int n_in,
                              void* d_out, int out_size, void* d_ws, size_t ws_size,
                              hipStream_t stream) {
    const float* x = (const float*)d_in[0];     // [B, N, D]
    const float* W = (const float*)d_in[1];     // [E, D]
    const float* bias = (const float*)d_in[2];  // [E]
    float* out = (float*)d_out;                 // [2*B*N] floats
    float* probs_t = (float*)d_ws;              // [B, E, N] fp32, 1 MB

    probs_kernel<<<BN / 64, 256, 0, stream>>>(x, W, bias, probs_t);
    route_kernel<<<B, 1024, 0, stream>>>(probs_t, out);
}